// Round 11
// baseline (349.490 us; speedup 1.0000x reference)
//
#include <hip/hip_runtime.h>

// 3-layer LSTM (B=1024, T=512, H=64), f16 MFMA, fp32 cell state.
// grid = 256 blocks x 4 batches; 768 threads = 12 waves = 3 layer-teams x 4.
// R11 = R10 + ROLE-STAGGERED sub-phases (anti-convoy): each phase k has two
// barriers; teams occupy opposite pipes in each sub-phase so the matrix pipe
// (MFMA waves) and trans/VALU pipe (activation waves) run CONCURRENTLY:
//   sub A: T0.mfma(k) | T1.mfma(k-1) | T2.act(k-3)+write
//   sub B: T0.act(k)+write | T1.act(k-1)+write | T2.mfma(k-2)
// T2's preacts persist in registers across barriers (act trails its mfma by
// one sub-phase pair). Dependency audit:
//   T0.mfma(k):   h0(k-1) written T0.act sub B phase k-1  (1 barrier away)
//   T1.mfma(k-1): h0(k-1) same; h1(k-2) written T1.act sub B phase k-1
//   T2.mfma(k-2): h1(k-2) written sub B phase k-1; h2(k-3) written sub A
//                 THIS phase (barrier 1 separates)
//   anti-dep: every slot's next overwrite is >= 2 sub-phases after its reads.
// L2 write-slot parity flips vs R10 (writes t=k-3, slot (k-1)&1); everything
// else byte-identical to R10.
// mfma_f32_16x16x32_f16: A row = lane&15 (batch l15>>2, 4-way broadcast),
// k-chunk = lane>>4; D col = lane&15 (unit), D row = (lane>>4)*4+reg ->
// acc[tt][0] on lane (l4,l15) IS the preact of cell (batch=l4, unit=w*16+l15).

typedef __attribute__((ext_vector_type(8))) _Float16 half8;
typedef __attribute__((ext_vector_type(4))) float floatx4;

static constexpr int T_STEPS = 512;

#define NL2E  (-1.4426950408889634f)   // -log2(e)
#define N2L2E (-2.8853900817779268f)   // -2*log2(e)

// LDS: per layer, 2-slot double buffer of h: [slot][4 bat][64 units] f16.
// addr = H_OFF(L) + slot*512 + ((bat*128 + unit*2) ^ ((bat&1)<<5)).
#define H_OFF0   0
#define H_OFF1   1024
#define H_OFF2   2048
#define SM_BYTES 3072

__device__ __forceinline__ floatx4 mfma16(half8 a, half8 b, floatx4 c) {
    return __builtin_amdgcn_mfma_f32_16x16x32_f16(a, b, c, 0, 0, 0);
}

__device__ __forceinline__ half8 cvt8s(const float* src, float s) {
    float4 v0 = *(const float4*)(src);
    float4 v1 = *(const float4*)(src + 4);
    half8 h;
    h[0] = (_Float16)(v0.x * s); h[1] = (_Float16)(v0.y * s);
    h[2] = (_Float16)(v0.z * s); h[3] = (_Float16)(v0.w * s);
    h[4] = (_Float16)(v1.x * s); h[5] = (_Float16)(v1.y * s);
    h[6] = (_Float16)(v1.z * s); h[7] = (_Float16)(v1.w * s);
    return h;
}

// h-writes visible to the block, WITHOUT draining vmcnt (x stays in flight).
__device__ __forceinline__ void lds_barrier() {
    asm volatile("s_waitcnt lgkmcnt(0)" ::: "memory");
    __builtin_amdgcn_s_barrier();
}

__global__ __launch_bounds__(768, 3) void lstm3_v11(
    const float* __restrict__ x,
    const float* __restrict__ w_ih0, const float* __restrict__ w_hh0,
    const float* __restrict__ b_ih0, const float* __restrict__ b_hh0,
    const float* __restrict__ w_ih1, const float* __restrict__ w_hh1,
    const float* __restrict__ b_ih1, const float* __restrict__ b_hh1,
    const float* __restrict__ w_ih2, const float* __restrict__ w_hh2,
    const float* __restrict__ b_ih2, const float* __restrict__ b_hh2,
    const float* __restrict__ w_lin, const float* __restrict__ b_lin,
    float* __restrict__ out)
{
    __shared__ __align__(16) char sm[SM_BYTES];

    const int tid  = threadIdx.x;
    const int lane = tid & 63;
    const int wave = tid >> 6;       // 0..11
    const int L    = wave >> 2;      // layer team 0..2
    const int w    = wave & 3;       // wave within team (unit group)
    const int l15  = lane & 15;
    const int l4   = lane >> 4;      // k-chunk; also this lane's BATCH in D
    const int bat  = l15 >> 2;       // A-row's batch (broadcast pattern)
    const int b0   = blockIdx.x * 4;
    const int u    = w * 16 + l15;   // this lane's hidden unit

    // ---- zero h buffers ----
    for (int i = tid; i < SM_BYTES / 16; i += 768)
        *(floatx4*)(&sm[i * 16]) = floatx4{0.f, 0.f, 0.f, 0.f};

    // ---- per-team parameter pointers ----
    const float* wi = (L == 0) ? w_ih0 : (L == 1 ? w_ih1 : w_ih2);
    const float* wh = (L == 0) ? w_hh0 : (L == 1 ? w_hh1 : w_hh2);
    const float* bi = (L == 0) ? b_ih0 : (L == 1 ? b_ih1 : b_ih2);
    const float* bh = (L == 0) ? b_hh0 : (L == 1 ? b_hh1 : b_hh2);
    const int HB = (L == 0) ? H_OFF0 : (L == 1 ? H_OFF1 : H_OFF2);
    const int PB = (L == 1) ? H_OFF0 : H_OFF1;   // prev-layer region (L>=1)

    // ---- register-resident weights, PRE-SCALED by -log2e (g: -2log2e) ----
    half8 wf[4][4];
#pragma unroll
    for (int tt = 0; tt < 4; ++tt) {
        const int g = tt * 64 + u;
        const float sc = (tt == 2) ? N2L2E : NL2E;
        if (L == 0) {
            half8 z;
#pragma unroll
            for (int j = 0; j < 8; ++j) z[j] = (_Float16)0.f;
            wf[tt][0] = (l4 < 3) ? cvt8s(w_ih0 + g * 24 + l4 * 8, sc) : z;
            wf[tt][1] = cvt8s(w_hh0 + g * 64 + l4 * 8, sc);
            wf[tt][2] = cvt8s(w_hh0 + g * 64 + 32 + l4 * 8, sc);
            wf[tt][3] = z;
        } else {
            wf[tt][0] = cvt8s(wi + g * 64 + l4 * 8, sc);
            wf[tt][1] = cvt8s(wi + g * 64 + 32 + l4 * 8, sc);
            wf[tt][2] = cvt8s(wh + g * 64 + l4 * 8, sc);
            wf[tt][3] = cvt8s(wh + g * 64 + 32 + l4 * 8, sc);
        }
    }
    // scaled bias as MFMA C-input; zero C for the second chain
    floatx4 bv[4];
#pragma unroll
    for (int tt = 0; tt < 4; ++tt) {
        const float sc = (tt == 2) ? N2L2E : NL2E;
        float b = sc * (bi[tt * 64 + u] + bh[tt * 64 + u]);
        bv[tt][0] = b; bv[tt][1] = b; bv[tt][2] = b; bv[tt][3] = b;
    }
    const floatx4 Z4 = floatx4{0.f, 0.f, 0.f, 0.f};

    // ---- per-lane LDS byte addresses ----
    const int swzR = (bat & 1) << 5;
    int rb0 = 0, rb1 = 0, rb2 = 0, rb3 = 0;
    if (L == 0) {
        rb1 = H_OFF0 + ((bat * 128 + 0  + l4 * 16) ^ swzR);  // own h, units 0-31
        rb2 = H_OFF0 + ((bat * 128 + 64 + l4 * 16) ^ swzR);  // own h, units 32-63
    } else {
        rb0 = PB + ((bat * 128 + 0  + l4 * 16) ^ swzR);      // h_{L-1}(t)
        rb1 = PB + ((bat * 128 + 64 + l4 * 16) ^ swzR);
        rb2 = HB + ((bat * 128 + 0  + l4 * 16) ^ swzR);      // own h(t-1)
        rb3 = HB + ((bat * 128 + 64 + l4 * 16) ^ swzR);
    }
    const int wb = HB + ((l4 * 128 + u * 2) ^ ((l4 & 1) << 5));

    // ---- hoisted per-parity addresses ----
    // L0/L1 (mfma at t=k-L): identical to R10. L2 (mfma at t=k-2):
    //   even k: h1(t) slot (k-2)&1=0, own h2(t-1) slot (k-3)&1=1,
    //           act write t=k-3 slot 1.
    const int par_e = L & 1;
    const int so_e = par_e * 512, sp_e = (par_e ^ 1) * 512;
    // even-k body:
    const int eA0 = rb0 + so_e;            // L>=1: prev-layer h(t)
    const int eA1 = rb1 + ((L == 0) ? sp_e : so_e);
    const int eA2 = rb2 + sp_e;            // own h(t-1)
    const int eA3 = rb3 + sp_e;
    const int eWr = wb + ((L == 2) ? sp_e : so_e);   // L2 act writes k-3 (flip)
    // odd-k body (parities flipped):
    const int oA0 = rb0 + sp_e;
    const int oA1 = rb1 + ((L == 0) ? so_e : sp_e);
    const int oA2 = rb2 + so_e;
    const int oA3 = rb3 + so_e;
    const int oWr = wb + ((L == 2) ? so_e : sp_e);

    // ---- x depth-2 register prefetch (team 0; l4==3 lanes stay zero pad) ----
    float4 xA0{0,0,0,0}, xA1{0,0,0,0}, xB0{0,0,0,0}, xB1{0,0,0,0};
    const bool xv = (L == 0) && (l4 < 3);
    const float* xpe = nullptr;
    const float* xpo = nullptr;
    if (xv) {
        const float* xb_ = x + (long)(b0 + bat) * T_STEPS * 24 + l4 * 8;
        xA0 = *(const float4*)(xb_);      xA1 = *(const float4*)(xb_ + 4);
        xB0 = *(const float4*)(xb_ + 24); xB1 = *(const float4*)(xb_ + 28);
        xpe = xb_ + 48;   // row t=2
        xpo = xb_ + 72;   // row t=3
    }

    float cst = 0.0f;    // fp32 cell state of (batch l4, unit u, layer L)
    float pre0 = 0.f, pre1 = 0.f, pre2 = 0.f, pre3 = 0.f;  // persists (L2)
    __syncthreads();     // setup visible (full drain, once)

    // ---- MFMA part: gate preacts -> pre0..3 ----
    auto do_mfma = [&](int t, int A0, int A1, int A2, int A3)
        __attribute__((always_inline)) {
        __builtin_amdgcn_s_setprio(1);
        if (L == 0) {
            const float4 v0 = (t & 1) ? xB0 : xA0;
            const float4 v1 = (t & 1) ? xB1 : xA1;
            half8 aX;
            aX[0] = (_Float16)v0.x; aX[1] = (_Float16)v0.y;
            aX[2] = (_Float16)v0.z; aX[3] = (_Float16)v0.w;
            aX[4] = (_Float16)v1.x; aX[5] = (_Float16)v1.y;
            aX[6] = (_Float16)v1.z; aX[7] = (_Float16)v1.w;
            half8 a1 = *(const half8*)(&sm[A1]);
            half8 a2 = *(const half8*)(&sm[A2]);
#pragma unroll
            for (int tt = 0; tt < 4; ++tt) {
                floatx4 accA = mfma16(aX, wf[tt][0], bv[tt]);
                floatx4 accB = mfma16(a1, wf[tt][1], Z4);
                accB = mfma16(a2, wf[tt][2], accB);
                float p = accA[0] + accB[0];
                if (tt == 0) pre0 = p; else if (tt == 1) pre1 = p;
                else if (tt == 2) pre2 = p; else pre3 = p;
            }
            if (xv && t + 2 < T_STEPS) {   // prefetch x(t+2), stays in flight
                if (t & 1) {
                    xB0 = *(const float4*)(xpo); xB1 = *(const float4*)(xpo + 4);
                    xpo += 48;
                } else {
                    xA0 = *(const float4*)(xpe); xA1 = *(const float4*)(xpe + 4);
                    xpe += 48;
                }
            }
        } else {
            half8 a0 = *(const half8*)(&sm[A0]);
            half8 a1 = *(const half8*)(&sm[A1]);
            half8 a2 = *(const half8*)(&sm[A2]);
            half8 a3 = *(const half8*)(&sm[A3]);
#pragma unroll
            for (int tt = 0; tt < 4; ++tt) {
                floatx4 accA = mfma16(a0, wf[tt][0], bv[tt]);
                floatx4 accB = mfma16(a2, wf[tt][2], Z4);
                accA = mfma16(a1, wf[tt][1], accA);
                accB = mfma16(a3, wf[tt][3], accB);
                float p = accA[0] + accB[0];
                if (tt == 0) pre0 = p; else if (tt == 1) pre1 = p;
                else if (tt == 2) pre2 = p; else pre3 = p;
            }
        }
        __builtin_amdgcn_s_setprio(0);
    };

    // ---- activation part: 1 cell/lane, pre = -(preact)*log2e ----
    auto do_act = [&](int WR) __attribute__((always_inline)) {
        float ei = __builtin_amdgcn_exp2f(pre0);
        float ef = __builtin_amdgcn_exp2f(pre1);
        float eg = __builtin_amdgcn_exp2f(pre2);
        float eo = __builtin_amdgcn_exp2f(pre3);
        float ig = __builtin_amdgcn_rcpf(1.f + ei);
        float fg = __builtin_amdgcn_rcpf(1.f + ef);
        float sg = __builtin_amdgcn_rcpf(1.f + eg);
        float og = __builtin_amdgcn_rcpf(1.f + eo);
        float gg = fmaf(2.f, sg, -1.f);                 // tanh(g)
        cst = fmaf(fg, cst, ig * gg);
        float et = __builtin_amdgcn_exp2f(cst * N2L2E);
        float th = fmaf(2.f, __builtin_amdgcn_rcpf(1.f + et), -1.f);
        float hv = og * th;
        *(_Float16*)(&sm[WR]) = (_Float16)hv;
    };

    auto phase = [&](int k, int A0, int A1, int A2, int A3, int WR)
        __attribute__((always_inline)) {
        // ---------------- sub A ----------------
        if (L < 2) {
            const int t = k - L;
            if ((unsigned)t < (unsigned)T_STEPS) do_mfma(t, A0, A1, A2, A3);
        } else {
            const int ta = k - 3;
            if ((unsigned)ta < (unsigned)T_STEPS) do_act(WR);
        }
        lds_barrier();
        // ---------------- sub B ----------------
        if (L < 2) {
            const int t = k - L;
            if ((unsigned)t < (unsigned)T_STEPS) do_act(WR);
        } else {
            const int tm = k - 2;
            if ((unsigned)tm < (unsigned)T_STEPS) do_mfma(tm, A0, A1, A2, A3);
        }
        lds_barrier();
    };

    // phases k = 0 .. 515 (T2's last act at k = 514)
    for (int k = 0; k < T_STEPS + 4; k += 2) {
        phase(k,     eA0, eA1, eA2, eA3, eWr);
        phase(k + 1, oA0, oA1, oA2, oA3, oWr);
    }

    __syncthreads();   // full drain before epilogue

    // ---- final linear: out[b,o] = h2(511) . w_lin[o,:] + b_lin[o] ----
    if (tid < 16) {
        const int bb = tid >> 2, o = tid & 3;
        const int sl = ((T_STEPS - 1) & 1) * 512;   // slot 1
        float accum = b_lin[o];
#pragma unroll
        for (int k = 0; k < 64; ++k) {
            const int off = H_OFF2 + sl + ((bb * 128 + k * 2) ^ ((bb & 1) << 5));
            accum = fmaf((float)*(const _Float16*)(&sm[off]), w_lin[o * 64 + k], accum);
        }
        out[(b0 + bb) * 4 + o] = accum;
    }
}

extern "C" void kernel_launch(void* const* d_in, const int* in_sizes, int n_in,
                              void* d_out, int out_size, void* d_ws, size_t ws_size,
                              hipStream_t stream) {
    const float* x     = (const float*)d_in[0];
    const float* w_ih0 = (const float*)d_in[1];
    const float* w_hh0 = (const float*)d_in[2];
    const float* b_ih0 = (const float*)d_in[3];
    const float* b_hh0 = (const float*)d_in[4];
    const float* w_ih1 = (const float*)d_in[5];
    const float* w_hh1 = (const float*)d_in[6];
    const float* b_ih1 = (const float*)d_in[7];
    const float* b_hh1 = (const float*)d_in[8];
    const float* w_ih2 = (const float*)d_in[9];
    const float* w_hh2 = (const float*)d_in[10];
    const float* b_ih2 = (const float*)d_in[11];
    const float* b_hh2 = (const float*)d_in[12];
    const float* w_lin = (const float*)d_in[13];
    const float* b_lin = (const float*)d_in[14];

    lstm3_v11<<<dim3(256), dim3(768), 0, stream>>>(
        x, w_ih0, w_hh0, b_ih0, b_hh0,
        w_ih1, w_hh1, b_ih1, b_hh1,
        w_ih2, w_hh2, b_ih2, b_hh2,
        w_lin, b_lin, (float*)d_out);
}

// Round 12
// 310.172 us; speedup vs baseline: 1.1268x; 1.1268x over previous
//
#include <hip/hip_runtime.h>

// 3-layer LSTM (B=1024, T=512, H=64), f16 MFMA, fp32 cell state.
// grid = 256 blocks x 4 batches; 768 threads = 12 waves = 3 layer-teams x 4.
// R12 = R10 with two changes aimed at giving the SIMD a co-issuable
// MFMA+VALU instruction mix (m114) instead of pure-phase convoys:
//  1. s_setprio removed (it brackets the MFMA region and fences scheduling).
//  2. The four exp2s of the activation are source-interleaved into the MFMA
//     region (each issued right after its gate's tt-chunk MFMAs complete),
//     leaving only rcp/cst/tanh/write as the serial tail.
// Everything else (skew pipeline, 1 lgkm-only barrier/step, x in registers,
// 2-deep split MFMA chains, pre-scaled weights, 2-slot h double buffer)
// identical to R10. Arithmetic identical -> absmax unchanged.
//
// mfma_f32_16x16x32_f16: A row = lane&15 (batch l15>>2, 4-way broadcast),
// k-chunk = lane>>4; D col = lane&15 (unit), D row = (lane>>4)*4+reg ->
// acc[tt][0] on lane (l4,l15) IS the preact of cell (batch=l4, unit=w*16+l15).
// Layout verified R2-R11.

typedef __attribute__((ext_vector_type(8))) _Float16 half8;
typedef __attribute__((ext_vector_type(4))) float floatx4;

static constexpr int T_STEPS = 512;

#define NL2E  (-1.4426950408889634f)   // -log2(e)
#define N2L2E (-2.8853900817779268f)   // -2*log2(e)

// LDS: per layer, 2-slot double buffer of h: [slot][4 bat][64 units] f16.
// addr = H_OFF(L) + slot*512 + ((bat*128 + unit*2) ^ ((bat&1)<<5)).
#define H_OFF0   0
#define H_OFF1   1024
#define H_OFF2   2048
#define SM_BYTES 3072

__device__ __forceinline__ floatx4 mfma16(half8 a, half8 b, floatx4 c) {
    return __builtin_amdgcn_mfma_f32_16x16x32_f16(a, b, c, 0, 0, 0);
}

__device__ __forceinline__ half8 cvt8s(const float* src, float s) {
    float4 v0 = *(const float4*)(src);
    float4 v1 = *(const float4*)(src + 4);
    half8 h;
    h[0] = (_Float16)(v0.x * s); h[1] = (_Float16)(v0.y * s);
    h[2] = (_Float16)(v0.z * s); h[3] = (_Float16)(v0.w * s);
    h[4] = (_Float16)(v1.x * s); h[5] = (_Float16)(v1.y * s);
    h[6] = (_Float16)(v1.z * s); h[7] = (_Float16)(v1.w * s);
    return h;
}

// h-writes visible to the block, WITHOUT draining vmcnt (x stays in flight).
__device__ __forceinline__ void lds_barrier() {
    asm volatile("s_waitcnt lgkmcnt(0)" ::: "memory");
    __builtin_amdgcn_s_barrier();
}

__global__ __launch_bounds__(768, 3) void lstm3_v12(
    const float* __restrict__ x,
    const float* __restrict__ w_ih0, const float* __restrict__ w_hh0,
    const float* __restrict__ b_ih0, const float* __restrict__ b_hh0,
    const float* __restrict__ w_ih1, const float* __restrict__ w_hh1,
    const float* __restrict__ b_ih1, const float* __restrict__ b_hh1,
    const float* __restrict__ w_ih2, const float* __restrict__ w_hh2,
    const float* __restrict__ b_ih2, const float* __restrict__ b_hh2,
    const float* __restrict__ w_lin, const float* __restrict__ b_lin,
    float* __restrict__ out)
{
    __shared__ __align__(16) char sm[SM_BYTES];

    const int tid  = threadIdx.x;
    const int lane = tid & 63;
    const int wave = tid >> 6;       // 0..11
    const int L    = wave >> 2;      // layer team 0..2
    const int w    = wave & 3;       // wave within team (unit group)
    const int l15  = lane & 15;
    const int l4   = lane >> 4;      // k-chunk; also this lane's BATCH in D
    const int bat  = l15 >> 2;       // A-row's batch (broadcast pattern)
    const int b0   = blockIdx.x * 4;
    const int u    = w * 16 + l15;   // this lane's hidden unit

    // ---- zero h buffers ----
    for (int i = tid; i < SM_BYTES / 16; i += 768)
        *(floatx4*)(&sm[i * 16]) = floatx4{0.f, 0.f, 0.f, 0.f};

    // ---- per-team parameter pointers ----
    const float* wi = (L == 0) ? w_ih0 : (L == 1 ? w_ih1 : w_ih2);
    const float* wh = (L == 0) ? w_hh0 : (L == 1 ? w_hh1 : w_hh2);
    const float* bi = (L == 0) ? b_ih0 : (L == 1 ? b_ih1 : b_ih2);
    const float* bh = (L == 0) ? b_hh0 : (L == 1 ? b_hh1 : b_hh2);
    const int HB = (L == 0) ? H_OFF0 : (L == 1 ? H_OFF1 : H_OFF2);
    const int PB = (L == 1) ? H_OFF0 : H_OFF1;   // prev-layer region (L>=1)

    // ---- register-resident weights, PRE-SCALED by -log2e (g: -2log2e) ----
    half8 wf[4][4];
#pragma unroll
    for (int tt = 0; tt < 4; ++tt) {
        const int g = tt * 64 + u;
        const float sc = (tt == 2) ? N2L2E : NL2E;
        if (L == 0) {
            half8 z;
#pragma unroll
            for (int j = 0; j < 8; ++j) z[j] = (_Float16)0.f;
            wf[tt][0] = (l4 < 3) ? cvt8s(w_ih0 + g * 24 + l4 * 8, sc) : z;
            wf[tt][1] = cvt8s(w_hh0 + g * 64 + l4 * 8, sc);
            wf[tt][2] = cvt8s(w_hh0 + g * 64 + 32 + l4 * 8, sc);
            wf[tt][3] = z;
        } else {
            wf[tt][0] = cvt8s(wi + g * 64 + l4 * 8, sc);
            wf[tt][1] = cvt8s(wi + g * 64 + 32 + l4 * 8, sc);
            wf[tt][2] = cvt8s(wh + g * 64 + l4 * 8, sc);
            wf[tt][3] = cvt8s(wh + g * 64 + 32 + l4 * 8, sc);
        }
    }
    // scaled bias as MFMA C-input; zero C for the second chain
    floatx4 bv[4];
#pragma unroll
    for (int tt = 0; tt < 4; ++tt) {
        const float sc = (tt == 2) ? N2L2E : NL2E;
        float b = sc * (bi[tt * 64 + u] + bh[tt * 64 + u]);
        bv[tt][0] = b; bv[tt][1] = b; bv[tt][2] = b; bv[tt][3] = b;
    }
    const floatx4 Z4 = floatx4{0.f, 0.f, 0.f, 0.f};

    // ---- per-lane LDS byte addresses ----
    const int swzR = (bat & 1) << 5;
    int rb0 = 0, rb1 = 0, rb2 = 0, rb3 = 0;
    if (L == 0) {
        rb1 = H_OFF0 + ((bat * 128 + 0  + l4 * 16) ^ swzR);  // own h, units 0-31
        rb2 = H_OFF0 + ((bat * 128 + 64 + l4 * 16) ^ swzR);  // own h, units 32-63
    } else {
        rb0 = PB + ((bat * 128 + 0  + l4 * 16) ^ swzR);      // h_{L-1}(t)
        rb1 = PB + ((bat * 128 + 64 + l4 * 16) ^ swzR);
        rb2 = HB + ((bat * 128 + 0  + l4 * 16) ^ swzR);      // own h(t-1)
        rb3 = HB + ((bat * 128 + 64 + l4 * 16) ^ swzR);
    }
    const int wb = HB + ((l4 * 128 + u * 2) ^ ((l4 & 1) << 5));

    // ---- hoisted per-parity addresses. Even phase s: par = (s-L)&1 = L&1 ----
    const int par_e = L & 1;
    const int so_e = par_e * 512, sp_e = (par_e ^ 1) * 512;
    // even body:
    const int eA0 = rb0 + so_e;            // L>=1: prev h(t)
    const int eA1 = rb1 + ((L == 0) ? sp_e : so_e);
    const int eA2 = rb2 + sp_e;            // own h(t-1)
    const int eA3 = rb3 + sp_e;
    const int eWr = wb + so_e;
    // odd body (parities flipped):
    const int oA0 = rb0 + sp_e;
    const int oA1 = rb1 + ((L == 0) ? so_e : sp_e);
    const int oA2 = rb2 + so_e;
    const int oA3 = rb3 + so_e;
    const int oWr = wb + sp_e;

    // ---- x depth-2 register prefetch (team 0; l4==3 lanes stay zero pad) ----
    float4 xA0{0,0,0,0}, xA1{0,0,0,0}, xB0{0,0,0,0}, xB1{0,0,0,0};
    const bool xv = (L == 0) && (l4 < 3);
    const float* xpe = nullptr;
    const float* xpo = nullptr;
    if (xv) {
        const float* xb_ = x + (long)(b0 + bat) * T_STEPS * 24 + l4 * 8;
        xA0 = *(const float4*)(xb_);      xA1 = *(const float4*)(xb_ + 4);
        xB0 = *(const float4*)(xb_ + 24); xB1 = *(const float4*)(xb_ + 28);
        xpe = xb_ + 48;   // row t=2
        xpo = xb_ + 72;   // row t=3
    }

    float cst = 0.0f;    // fp32 cell state of (batch l4, unit u, layer L)
    __syncthreads();     // setup visible (full drain, once)

    auto body = [&](int s, int A0, int A1, int A2, int A3, int WR)
        __attribute__((always_inline)) {
        const int t = s - L;
        const bool active = ((unsigned)t < (unsigned)T_STEPS);

        if (active) {
            // exp2 of each gate issued right after its tt-chunk's MFMAs:
            // gives the scheduler a co-issuable MFMA+VALU/trans mix.
            float e0, e1, e2, e3;
            if (L == 0) {
                const float4 v0 = (t & 1) ? xB0 : xA0;
                const float4 v1 = (t & 1) ? xB1 : xA1;
                half8 aX;
                aX[0] = (_Float16)v0.x; aX[1] = (_Float16)v0.y;
                aX[2] = (_Float16)v0.z; aX[3] = (_Float16)v0.w;
                aX[4] = (_Float16)v1.x; aX[5] = (_Float16)v1.y;
                aX[6] = (_Float16)v1.z; aX[7] = (_Float16)v1.w;
                half8 a1 = *(const half8*)(&sm[A1]);
                half8 a2 = *(const half8*)(&sm[A2]);
#pragma unroll
                for (int tt = 0; tt < 4; ++tt) {
                    floatx4 accA = mfma16(aX, wf[tt][0], bv[tt]);
                    floatx4 accB = mfma16(a1, wf[tt][1], Z4);
                    accB = mfma16(a2, wf[tt][2], accB);
                    float e = __builtin_amdgcn_exp2f(accA[0] + accB[0]);
                    if (tt == 0) e0 = e; else if (tt == 1) e1 = e;
                    else if (tt == 2) e2 = e; else e3 = e;
                }
                if (xv && t + 2 < T_STEPS) {   // prefetch x(t+2), stays in flight
                    if (t & 1) {
                        xB0 = *(const float4*)(xpo); xB1 = *(const float4*)(xpo + 4);
                        xpo += 48;
                    } else {
                        xA0 = *(const float4*)(xpe); xA1 = *(const float4*)(xpe + 4);
                        xpe += 48;
                    }
                }
            } else {
                half8 a0 = *(const half8*)(&sm[A0]);
                half8 a1 = *(const half8*)(&sm[A1]);
                half8 a2 = *(const half8*)(&sm[A2]);
                half8 a3 = *(const half8*)(&sm[A3]);
#pragma unroll
                for (int tt = 0; tt < 4; ++tt) {
                    floatx4 accA = mfma16(a0, wf[tt][0], bv[tt]);
                    floatx4 accB = mfma16(a2, wf[tt][2], Z4);
                    accA = mfma16(a1, wf[tt][1], accA);
                    accB = mfma16(a3, wf[tt][3], accB);
                    float e = __builtin_amdgcn_exp2f(accA[0] + accB[0]);
                    if (tt == 0) e0 = e; else if (tt == 1) e1 = e;
                    else if (tt == 2) e2 = e; else e3 = e;
                }
            }

            // short combine tail: 4 rcp + cst + tanh + write
            float ig = __builtin_amdgcn_rcpf(1.f + e0);
            float fg = __builtin_amdgcn_rcpf(1.f + e1);
            float sg = __builtin_amdgcn_rcpf(1.f + e2);
            float og = __builtin_amdgcn_rcpf(1.f + e3);
            float gg = fmaf(2.f, sg, -1.f);                 // tanh(g)
            cst = fmaf(fg, cst, ig * gg);
            float et = __builtin_amdgcn_exp2f(cst * N2L2E);
            float th = fmaf(2.f, __builtin_amdgcn_rcpf(1.f + et), -1.f);
            float hv = og * th;
            *(_Float16*)(&sm[WR]) = (_Float16)hv;
        }
        lds_barrier();   // h(t) visible; vmcnt NOT drained (x stays in flight)
    };

    for (int s = 0; s < T_STEPS + 2; s += 2) {
        body(s,     eA0, eA1, eA2, eA3, eWr);
        body(s + 1, oA0, oA1, oA2, oA3, oWr);
    }

    __syncthreads();   // full drain before epilogue

    // ---- final linear: out[b,o] = h2(511) . w_lin[o,:] + b_lin[o] ----
    if (tid < 16) {
        const int bb = tid >> 2, o = tid & 3;
        const int sl = ((T_STEPS - 1) & 1) * 512;   // slot 1
        float accum = b_lin[o];
#pragma unroll
        for (int k = 0; k < 64; ++k) {
            const int off = H_OFF2 + sl + ((bb * 128 + k * 2) ^ ((bb & 1) << 5));
            accum = fmaf((float)*(const _Float16*)(&sm[off]), w_lin[o * 64 + k], accum);
        }
        out[(b0 + bb) * 4 + o] = accum;
    }
}

extern "C" void kernel_launch(void* const* d_in, const int* in_sizes, int n_in,
                              void* d_out, int out_size, void* d_ws, size_t ws_size,
                              hipStream_t stream) {
    const float* x     = (const float*)d_in[0];
    const float* w_ih0 = (const float*)d_in[1];
    const float* w_hh0 = (const float*)d_in[2];
    const float* b_ih0 = (const float*)d_in[3];
    const float* b_hh0 = (const float*)d_in[4];
    const float* w_ih1 = (const float*)d_in[5];
    const float* w_hh1 = (const float*)d_in[6];
    const float* b_ih1 = (const float*)d_in[7];
    const float* b_hh1 = (const float*)d_in[8];
    const float* w_ih2 = (const float*)d_in[9];
    const float* w_hh2 = (const float*)d_in[10];
    const float* b_ih2 = (const float*)d_in[11];
    const float* b_hh2 = (const float*)d_in[12];
    const float* w_lin = (const float*)d_in[13];
    const float* b_lin = (const float*)d_in[14];

    lstm3_v12<<<dim3(256), dim3(768), 0, stream>>>(
        x, w_ih0, w_hh0, b_ih0, b_hh0,
        w_ih1, w_hh1, b_ih1, b_hh1,
        w_ih2, w_hh2, b_ih2, b_hh2,
        w_lin, b_lin, (float*)d_out);
}